// Round 1
// baseline (649.648 us; speedup 1.0000x reference)
//
#include <hip/hip_runtime.h>
#include <hip/hip_bf16.h>

// Problem constants (B,N,HC,HH,K,D) = (64,300,64,64,3,10)
#define BB 64
#define NN 300
#define HH 64
#define RTOT (BB*NN)          // 19200 rows
#define KIO  (3*HH*HH)        // 12288: weights_pool inner size per d
#define JOUT (HH*HH)          // 4096 output cols

__device__ inline float tanh_fast(float x) {
    float e = __expf(2.f * x);
    return 1.f - 2.f * __builtin_amdgcn_rcpf(e + 1.f);
}

// A[n,m] = softmax_m( relu(E[n]·E[m]) ), one block per row n
__global__ __launch_bounds__(256) void k_adjacency(const float* __restrict__ E,
                                                   float* __restrict__ A) {
    __shared__ float sE[16];
    __shared__ float row[NN];
    __shared__ float red[256];
    int n = blockIdx.x, tid = threadIdx.x;
    if (tid < 10) sE[tid] = E[n*10 + tid];
    __syncthreads();
    float lmax = -1e30f;
    for (int m = tid; m < NN; m += 256) {
        float s = 0.f;
        #pragma unroll
        for (int d = 0; d < 10; ++d) s += sE[d] * E[m*10 + d];
        s = fmaxf(s, 0.f);
        row[m] = s;
        lmax = fmaxf(lmax, s);
    }
    red[tid] = lmax; __syncthreads();
    for (int off = 128; off > 0; off >>= 1) {
        if (tid < off) red[tid] = fmaxf(red[tid], red[tid+off]);
        __syncthreads();
    }
    float mx = red[0]; __syncthreads();
    float lsum = 0.f;
    for (int m = tid; m < NN; m += 256) {
        float e = __expf(row[m] - mx);
        row[m] = e;
        lsum += e;
    }
    red[tid] = lsum; __syncthreads();
    for (int off = 128; off > 0; off >>= 1) {
        if (tid < off) red[tid] += red[tid+off];
        __syncthreads();
    }
    float inv = 1.f / red[0];
    for (int m = tid; m < NN; m += 256) A[n*NN + m] = row[m] * inv;
}

// T2 = 2*A@A - I
__global__ __launch_bounds__(256) void k_cheb(const float* __restrict__ A,
                                              float* __restrict__ T2) {
    int idx = blockIdx.x*256 + threadIdx.x;
    if (idx >= NN*NN) return;
    int n = idx / NN, m = idx % NN;
    float s = 0.f;
    for (int l = 0; l < NN; ++l) s += A[n*NN + l] * A[l*NN + m];
    T2[idx] = 2.f*s - (n == m ? 1.f : 0.f);
}

// Wn[n, kio] = sum_d E[n,d] * pool[d, kio]   (3,686,400 elements)
__global__ __launch_bounds__(256) void k_node_weights(const float* __restrict__ E,
                                                      const float* __restrict__ pool,
                                                      float* __restrict__ Wn) {
    int idx = blockIdx.x*256 + threadIdx.x;   // exact: 14400*256
    int n = idx / KIO, kio = idx % KIO;
    float s = 0.f;
    #pragma unroll
    for (int d = 0; d < 10; ++d) s += E[n*10 + d] * pool[d*KIO + kio];
    Wn[idx] = s;
}

// bN[n,o] = sum_d E[n,d] * bpool[d,o]
__global__ __launch_bounds__(256) void k_node_bias(const float* __restrict__ E,
                                                   const float* __restrict__ bpool,
                                                   float* __restrict__ bN) {
    int idx = blockIdx.x*256 + threadIdx.x;   // exact: 75*256 = 19200
    int n = idx >> 6, o = idx & 63;
    float s = 0.f;
    #pragma unroll
    for (int d = 0; d < 10; ++d) s += E[n*10 + d] * bpool[d*64 + o];
    bN[idx] = s;
}

// h[r,o] = relu( z[r,:]·W_in[o,:] + b_in[o] )  -- 64r x 64o tile per block
__global__ __launch_bounds__(256) void k_in_proj(const float* __restrict__ z,
                                                 const float* __restrict__ Win,
                                                 const float* __restrict__ bin,
                                                 float* __restrict__ h) {
    __shared__ float Wt[64*68];   // Wt[c*68 + o] = Win[o*64 + c]
    __shared__ float zl[64*66];   // zl[rr*66 + c]
    int tx = threadIdx.x, ty = threadIdx.y;   // 16 x 16
    int tid = ty*16 + tx;
    int r0 = blockIdx.y * 64;
    for (int e = tid; e < 4096; e += 256) {
        int o = e >> 6, c = e & 63;
        Wt[c*68 + o] = Win[e];
        zl[o*66 + c] = z[(r0 + o)*64 + c];   // reuse o as rr
    }
    __syncthreads();
    float4 bo = *(const float4*)&bin[tx*4];
    float acc[4][4];
    #pragma unroll
    for (int s = 0; s < 4; ++s) { acc[s][0]=bo.x; acc[s][1]=bo.y; acc[s][2]=bo.z; acc[s][3]=bo.w; }
    const float* zr = &zl[(ty*4)*66];
    for (int c = 0; c < 64; ++c) {
        float4 w = *(const float4*)&Wt[c*68 + tx*4];
        float z0 = zr[c], z1 = zr[66+c], z2 = zr[132+c], z3 = zr[198+c];
        acc[0][0] += z0*w.x; acc[0][1] += z0*w.y; acc[0][2] += z0*w.z; acc[0][3] += z0*w.w;
        acc[1][0] += z1*w.x; acc[1][1] += z1*w.y; acc[1][2] += z1*w.z; acc[1][3] += z1*w.w;
        acc[2][0] += z2*w.x; acc[2][1] += z2*w.y; acc[2][2] += z2*w.z; acc[2][3] += z2*w.w;
        acc[3][0] += z3*w.x; acc[3][1] += z3*w.y; acc[3][2] += z3*w.z; acc[3][3] += z3*w.w;
    }
    #pragma unroll
    for (int s = 0; s < 4; ++s) {
        float4 v = make_float4(fmaxf(acc[s][0],0.f), fmaxf(acc[s][1],0.f),
                               fmaxf(acc[s][2],0.f), fmaxf(acc[s][3],0.f));
        *(float4*)&h[(r0 + ty*4 + s)*64 + tx*4] = v;
    }
}

// xg1[b,n,c] = sum_m A[n,m] h[b,m,c]; xg2 same with T2. 4 n x 64 c per block.
__global__ __launch_bounds__(256) void k_spatial(const float* __restrict__ A,
                                                 const float* __restrict__ T2,
                                                 const float* __restrict__ h,
                                                 float* __restrict__ xg1,
                                                 float* __restrict__ xg2) {
    int tid = threadIdx.x;
    int c = tid & 63, tn = tid >> 6;
    int n = blockIdx.x*4 + tn, b = blockIdx.y;
    const float* r1 = A  + n*NN;
    const float* r2 = T2 + n*NN;
    const float* hb = h + (size_t)b*NN*64 + c;
    float a1 = 0.f, a2 = 0.f;
    for (int m = 0; m < NN; ++m) {
        float hv = hb[m*64];
        a1 += r1[m]*hv;
        a2 += r2[m]*hv;
    }
    int off = (b*NN + n)*64 + c;
    xg1[off] = a1;
    xg2[off] = a2;
}

// h2[b,n,o] = bN[n,o] + sum_{ki} xg[b,n,ki] * Wn[n,ki,o]; k=0 slice is h itself.
__global__ __launch_bounds__(256) void k_node_mm(const float* __restrict__ h,
                                                 const float* __restrict__ xg1,
                                                 const float* __restrict__ xg2,
                                                 const float* __restrict__ Wn,
                                                 const float* __restrict__ bN,
                                                 float* __restrict__ h2) {
    __shared__ float Wnl[192*64];   // 48 KB
    __shared__ float xgl[8][192];
    int tid = threadIdx.x;
    int o = tid & 63, ty = tid >> 6;
    int n = blockIdx.x, b0 = blockIdx.y*8;
    for (int e = tid; e < 12288; e += 256) Wnl[e] = Wn[(size_t)n*KIO + e];
    for (int e = tid; e < 8*192; e += 256) {
        int bb = e / 192, ki = e % 192;
        int k = ki >> 6, i = ki & 63;
        const float* src = (k == 0) ? h : ((k == 1) ? xg1 : xg2);
        xgl[bb][ki] = src[((b0+bb)*NN + n)*64 + i];
    }
    __syncthreads();
    float bias = bN[n*64 + o];
    for (int bb = ty; bb < 8; bb += 4) {
        float acc = bias;
        for (int ki = 0; ki < 192; ++ki) acc += xgl[bb][ki] * Wnl[ki*64 + o];
        h2[((b0+bb)*NN + n)*64 + o] = acc;
    }
}

// out[r,j] = tanh( h2[r,:]·Wout[j,:] + bout[j] ), r<19200, j<4096.
// 64r x 64j tile per block, 4x4 register blocking per thread.
__global__ __launch_bounds__(256) void k_out_proj(const float* __restrict__ h2,
                                                  const float* __restrict__ Wout,
                                                  const float* __restrict__ bout,
                                                  float* __restrict__ out) {
    __shared__ float Wt[64*68];   // Wt[i*68 + jj] = Wout[(j0+jj)*64 + i]
    __shared__ float hl[64*66];   // hl[rr*66 + i]
    int tx = threadIdx.x, ty = threadIdx.y;   // 16 x 16
    int tid = ty*16 + tx;
    int j0 = blockIdx.x * 64, r0 = blockIdx.y * 64;
    for (int e = tid; e < 4096; e += 256) {
        int jj = e >> 6, i = e & 63;
        Wt[i*68 + jj] = Wout[(j0+jj)*64 + i];
        hl[jj*66 + i] = h2[(r0+jj)*64 + i];   // reuse jj as rr
    }
    __syncthreads();
    float4 bo = *(const float4*)&bout[j0 + tx*4];
    float acc[4][4];
    #pragma unroll
    for (int s = 0; s < 4; ++s) { acc[s][0]=bo.x; acc[s][1]=bo.y; acc[s][2]=bo.z; acc[s][3]=bo.w; }
    const float* hr = &hl[(ty*4)*66];
    for (int i = 0; i < 64; ++i) {
        float4 w = *(const float4*)&Wt[i*68 + tx*4];
        float h0 = hr[i], h1 = hr[66+i], h2v = hr[132+i], h3 = hr[198+i];
        acc[0][0] += h0*w.x; acc[0][1] += h0*w.y; acc[0][2] += h0*w.z; acc[0][3] += h0*w.w;
        acc[1][0] += h1*w.x; acc[1][1] += h1*w.y; acc[1][2] += h1*w.z; acc[1][3] += h1*w.w;
        acc[2][0] += h2v*w.x; acc[2][1] += h2v*w.y; acc[2][2] += h2v*w.z; acc[2][3] += h2v*w.w;
        acc[3][0] += h3*w.x; acc[3][1] += h3*w.y; acc[3][2] += h3*w.z; acc[3][3] += h3*w.w;
    }
    #pragma unroll
    for (int s = 0; s < 4; ++s) {
        float4 v = make_float4(tanh_fast(acc[s][0]), tanh_fast(acc[s][1]),
                               tanh_fast(acc[s][2]), tanh_fast(acc[s][3]));
        *(float4*)&out[(size_t)(r0 + ty*4 + s)*JOUT + j0 + tx*4] = v;
    }
}

extern "C" void kernel_launch(void* const* d_in, const int* in_sizes, int n_in,
                              void* d_out, int out_size, void* d_ws, size_t ws_size,
                              hipStream_t stream) {
    const float* z     = (const float*)d_in[0];   // [64,300,64]
    const float* Win   = (const float*)d_in[1];   // [64,64]
    const float* bin   = (const float*)d_in[2];   // [64]
    const float* Wout  = (const float*)d_in[3];   // [4096,64]
    const float* bout  = (const float*)d_in[4];   // [4096]
    const float* E     = (const float*)d_in[5];   // [300,10]
    const float* pool  = (const float*)d_in[6];   // [10,3,64,64]
    const float* bpool = (const float*)d_in[7];   // [10,64]
    float* out = (float*)d_out;                   // [64,300,64,64]

    float* ws  = (float*)d_ws;
    float* A   = ws;                 // 90,000
    float* T2  = A   + 90000;        // 90,000
    float* Wn  = T2  + 90000;        // 3,686,400
    float* bN  = Wn  + 3686400;      // 19,200
    float* h   = bN  + 19200;        // 1,228,800
    float* xg1 = h   + 1228800;      // 1,228,800
    float* xg2 = xg1 + 1228800;      // 1,228,800
    float* h2  = xg2 + 1228800;      // 1,228,800  (total ~35.2 MB)

    k_adjacency   <<<NN, 256, 0, stream>>>(E, A);
    k_cheb        <<<(NN*NN + 255)/256, 256, 0, stream>>>(A, T2);
    k_node_weights<<<14400, 256, 0, stream>>>(E, pool, Wn);
    k_node_bias   <<<75, 256, 0, stream>>>(E, bpool, bN);
    k_in_proj     <<<dim3(1, RTOT/64), dim3(16,16), 0, stream>>>(z, Win, bin, h);
    k_spatial     <<<dim3(NN/4, BB), 256, 0, stream>>>(A, T2, h, xg1, xg2);
    k_node_mm     <<<dim3(NN, 8), 256, 0, stream>>>(h, xg1, xg2, Wn, bN, h2);
    k_out_proj    <<<dim3(JOUT/64, RTOT/64), dim3(16,16), 0, stream>>>(h2, Wout, bout, out);
}

// Round 3
// 562.453 us; speedup vs baseline: 1.1550x; 1.1550x over previous
//
#include <hip/hip_runtime.h>
#include <hip/hip_bf16.h>

// Problem constants (B,N,HC,HH,K,D) = (64,300,64,64,3,10)
#define BB 64
#define NN 300
#define HH 64
#define RTOT (BB*NN)          // 19200 rows
#define KIO  (3*HH*HH)        // 12288: weights_pool inner size per d
#define JOUT (HH*HH)          // 4096 output cols

typedef __attribute__((ext_vector_type(8))) _Float16 f16x8;
typedef __attribute__((ext_vector_type(4))) float floatx4;

__device__ inline float tanh_fast(float x) {
    float e = __expf(2.f * x);
    return 1.f - 2.f * __builtin_amdgcn_rcpf(e + 1.f);
}

// A[n,m] = softmax_m( relu(E[n]·E[m]) ), one block per row n
__global__ __launch_bounds__(256) void k_adjacency(const float* __restrict__ E,
                                                   float* __restrict__ A) {
    __shared__ float sE[16];
    __shared__ float row[NN];
    __shared__ float red[256];
    int n = blockIdx.x, tid = threadIdx.x;
    if (tid < 10) sE[tid] = E[n*10 + tid];
    __syncthreads();
    float lmax = -1e30f;
    for (int m = tid; m < NN; m += 256) {
        float s = 0.f;
        #pragma unroll
        for (int d = 0; d < 10; ++d) s += sE[d] * E[m*10 + d];
        s = fmaxf(s, 0.f);
        row[m] = s;
        lmax = fmaxf(lmax, s);
    }
    red[tid] = lmax; __syncthreads();
    for (int off = 128; off > 0; off >>= 1) {
        if (tid < off) red[tid] = fmaxf(red[tid], red[tid+off]);
        __syncthreads();
    }
    float mx = red[0]; __syncthreads();
    float lsum = 0.f;
    for (int m = tid; m < NN; m += 256) {
        float e = __expf(row[m] - mx);
        row[m] = e;
        lsum += e;
    }
    red[tid] = lsum; __syncthreads();
    for (int off = 128; off > 0; off >>= 1) {
        if (tid < off) red[tid] += red[tid+off];
        __syncthreads();
    }
    float inv = 1.f / red[0];
    for (int m = tid; m < NN; m += 256) A[n*NN + m] = row[m] * inv;
}

// T2 = 2*A@A - I
__global__ __launch_bounds__(256) void k_cheb(const float* __restrict__ A,
                                              float* __restrict__ T2) {
    int idx = blockIdx.x*256 + threadIdx.x;
    if (idx >= NN*NN) return;
    int n = idx / NN, m = idx % NN;
    float s = 0.f;
    for (int l = 0; l < NN; ++l) s += A[n*NN + l] * A[l*NN + m];
    T2[idx] = 2.f*s - (n == m ? 1.f : 0.f);
}

// Wn[n, kio] = sum_d E[n,d] * pool[d, kio]   (3,686,400 elements)
__global__ __launch_bounds__(256) void k_node_weights(const float* __restrict__ E,
                                                      const float* __restrict__ pool,
                                                      float* __restrict__ Wn) {
    int idx = blockIdx.x*256 + threadIdx.x;   // exact: 14400*256
    int n = idx / KIO, kio = idx % KIO;
    float s = 0.f;
    #pragma unroll
    for (int d = 0; d < 10; ++d) s += E[n*10 + d] * pool[d*KIO + kio];
    Wn[idx] = s;
}

// bN[n,o] = sum_d E[n,d] * bpool[d,o]
__global__ __launch_bounds__(256) void k_node_bias(const float* __restrict__ E,
                                                   const float* __restrict__ bpool,
                                                   float* __restrict__ bN) {
    int idx = blockIdx.x*256 + threadIdx.x;   // exact: 75*256 = 19200
    int n = idx >> 6, o = idx & 63;
    float s = 0.f;
    #pragma unroll
    for (int d = 0; d < 10; ++d) s += E[n*10 + d] * bpool[d*64 + o];
    bN[idx] = s;
}

// Wout fp32 -> fp16 (262144 elems)
__global__ __launch_bounds__(256) void k_cvt_wout(const float* __restrict__ W,
                                                  _Float16* __restrict__ Wh) {
    int idx = blockIdx.x*256 + threadIdx.x;   // exact: 1024*256
    Wh[idx] = (_Float16)W[idx];
}

// h[r,o] = relu( z[r,:]·W_in[o,:] + b_in[o] )  -- 64r x 64o tile per block
__global__ __launch_bounds__(256) void k_in_proj(const float* __restrict__ z,
                                                 const float* __restrict__ Win,
                                                 const float* __restrict__ bin,
                                                 float* __restrict__ h) {
    __shared__ float Wt[64*68];   // Wt[c*68 + o] = Win[o*64 + c]
    __shared__ float zl[64*66];   // zl[rr*66 + c]
    int tx = threadIdx.x, ty = threadIdx.y;   // 16 x 16
    int tid = ty*16 + tx;
    int r0 = blockIdx.y * 64;
    for (int e = tid; e < 4096; e += 256) {
        int o = e >> 6, c = e & 63;
        Wt[c*68 + o] = Win[e];
        zl[o*66 + c] = z[(r0 + o)*64 + c];   // reuse o as rr
    }
    __syncthreads();
    float4 bo = *(const float4*)&bin[tx*4];
    float acc[4][4];
    #pragma unroll
    for (int s = 0; s < 4; ++s) { acc[s][0]=bo.x; acc[s][1]=bo.y; acc[s][2]=bo.z; acc[s][3]=bo.w; }
    const float* zr = &zl[(ty*4)*66];
    for (int c = 0; c < 64; ++c) {
        float4 w = *(const float4*)&Wt[c*68 + tx*4];
        float z0 = zr[c], z1 = zr[66+c], z2 = zr[132+c], z3 = zr[198+c];
        acc[0][0] += z0*w.x; acc[0][1] += z0*w.y; acc[0][2] += z0*w.z; acc[0][3] += z0*w.w;
        acc[1][0] += z1*w.x; acc[1][1] += z1*w.y; acc[1][2] += z1*w.z; acc[1][3] += z1*w.w;
        acc[2][0] += z2*w.x; acc[2][1] += z2*w.y; acc[2][2] += z2*w.z; acc[2][3] += z2*w.w;
        acc[3][0] += z3*w.x; acc[3][1] += z3*w.y; acc[3][2] += z3*w.z; acc[3][3] += z3*w.w;
    }
    #pragma unroll
    for (int s = 0; s < 4; ++s) {
        float4 v = make_float4(fmaxf(acc[s][0],0.f), fmaxf(acc[s][1],0.f),
                               fmaxf(acc[s][2],0.f), fmaxf(acc[s][3],0.f));
        *(float4*)&h[(r0 + ty*4 + s)*64 + tx*4] = v;
    }
}

// xg1[b,n,c] = sum_m A[n,m] h[b,m,c]; xg2 same with T2. 4 n x 64 c per block.
__global__ __launch_bounds__(256) void k_spatial(const float* __restrict__ A,
                                                 const float* __restrict__ T2,
                                                 const float* __restrict__ h,
                                                 float* __restrict__ xg1,
                                                 float* __restrict__ xg2) {
    int tid = threadIdx.x;
    int c = tid & 63, tn = tid >> 6;
    int n = blockIdx.x*4 + tn, b = blockIdx.y;
    const float* r1 = A  + n*NN;
    const float* r2 = T2 + n*NN;
    const float* hb = h + (size_t)b*NN*64 + c;
    float a1 = 0.f, a2 = 0.f;
    for (int m = 0; m < NN; ++m) {
        float hv = hb[m*64];
        a1 += r1[m]*hv;
        a2 += r2[m]*hv;
    }
    int off = (b*NN + n)*64 + c;
    xg1[off] = a1;
    xg2[off] = a2;
}

// h2[b,n,o] = bN[n,o] + sum_{ki} xg[b,n,ki] * Wn[n,ki,o]; k=0 slice is h itself.
// Output written as fp16 for the MFMA out-proj.
__global__ __launch_bounds__(256) void k_node_mm(const float* __restrict__ h,
                                                 const float* __restrict__ xg1,
                                                 const float* __restrict__ xg2,
                                                 const float* __restrict__ Wn,
                                                 const float* __restrict__ bN,
                                                 _Float16* __restrict__ h2h) {
    __shared__ float Wnl[192*64];   // 48 KB
    __shared__ float xgl[8][192];
    int tid = threadIdx.x;
    int o = tid & 63, ty = tid >> 6;
    int n = blockIdx.x, b0 = blockIdx.y*8;
    for (int e = tid; e < 12288; e += 256) Wnl[e] = Wn[(size_t)n*KIO + e];
    for (int e = tid; e < 8*192; e += 256) {
        int bb = e / 192, ki = e % 192;
        int k = ki >> 6, i = ki & 63;
        const float* src = (k == 0) ? h : ((k == 1) ? xg1 : xg2);
        xgl[bb][ki] = src[((b0+bb)*NN + n)*64 + i];
    }
    __syncthreads();
    float bias = bN[n*64 + o];
    for (int bb = ty; bb < 8; bb += 4) {
        float acc = bias;
        for (int ki = 0; ki < 192; ++ki) acc += xgl[bb][ki] * Wnl[ki*64 + o];
        h2h[((b0+bb)*NN + n)*64 + o] = (_Float16)acc;
    }
}

// out[r,j] = tanh( h2[r,:]·Wout[j,:] + bout[j] ), r<19200, j<4096.
// fp16 MFMA 16x16x32, K=64 = 2 k-steps. Fragments loaded straight from
// global (A[m=lane&15][k=quad*8+j] layout -> 16B contiguous per lane),
// no LDS. Block = 4 waves in 2x2, 128x128 tile; wave = 64x64 (4x4 frags).
__global__ __launch_bounds__(256) void k_out_proj_mfma(const _Float16* __restrict__ h2h,
                                                       const _Float16* __restrict__ Wh,
                                                       const float* __restrict__ bout,
                                                       float* __restrict__ out) {
    int tid  = threadIdx.x;
    int wave = tid >> 6, lane = tid & 63;
    int quad = lane >> 4, lr = lane & 15;
    int m0 = blockIdx.y*128 + (wave >> 1)*64;
    int n0 = blockIdx.x*128 + (wave & 1)*64;
    floatx4 acc[4][4] = {};   // [m-frag][n-frag]
    const _Float16* Aptr = h2h + (size_t)(m0 + lr)*64 + quad*8;
    const _Float16* Bptr = Wh  + (size_t)(n0 + lr)*64 + quad*8;
    #pragma unroll
    for (int ks = 0; ks < 2; ++ks) {
        f16x8 a[4], b[4];
        #pragma unroll
        for (int f = 0; f < 4; ++f) {
            a[f] = *(const f16x8*)(Aptr + (size_t)f*16*64 + ks*32);
            b[f] = *(const f16x8*)(Bptr + (size_t)f*16*64 + ks*32);
        }
        #pragma unroll
        for (int mf = 0; mf < 4; ++mf)
            #pragma unroll
            for (int nf = 0; nf < 4; ++nf)
                acc[mf][nf] = __builtin_amdgcn_mfma_f32_16x16x32_f16(a[mf], b[nf], acc[mf][nf], 0, 0, 0);
    }
    // C/D layout: col = lane&15, row = quad*4 + reg  [m89-verified, dtype-indep]
    #pragma unroll
    for (int nf = 0; nf < 4; ++nf) {
        int col = n0 + nf*16 + lr;
        float bj = bout[col];
        #pragma unroll
        for (int mf = 0; mf < 4; ++mf) {
            int row = m0 + mf*16 + quad*4;
            #pragma unroll
            for (int r = 0; r < 4; ++r)
                out[(size_t)(row + r)*JOUT + col] = tanh_fast(acc[mf][nf][r] + bj);
        }
    }
}

extern "C" void kernel_launch(void* const* d_in, const int* in_sizes, int n_in,
                              void* d_out, int out_size, void* d_ws, size_t ws_size,
                              hipStream_t stream) {
    const float* z     = (const float*)d_in[0];   // [64,300,64]
    const float* Win   = (const float*)d_in[1];   // [64,64]
    const float* bin   = (const float*)d_in[2];   // [64]
    const float* Wout  = (const float*)d_in[3];   // [4096,64]
    const float* bout  = (const float*)d_in[4];   // [4096]
    const float* E     = (const float*)d_in[5];   // [300,10]
    const float* pool  = (const float*)d_in[6];   // [10,3,64,64]
    const float* bpool = (const float*)d_in[7];   // [10,64]
    float* out = (float*)d_out;                   // [64,300,64,64]

    float* ws  = (float*)d_ws;
    float* A   = ws;                 // 90,000
    float* T2  = A   + 90000;        // 90,000
    float* Wn  = T2  + 90000;        // 3,686,400
    float* bN  = Wn  + 3686400;      // 19,200
    float* h   = bN  + 19200;        // 1,228,800
    float* xg1 = h   + 1228800;      // 1,228,800
    float* xg2 = xg1 + 1228800;      // 1,228,800
    _Float16* h2h  = (_Float16*)(xg2 + 1228800);  // 1,228,800 fp16
    _Float16* Wouth = h2h + 1228800;              // 262,144 fp16  (total ~33.3 MB)

    k_adjacency   <<<NN, 256, 0, stream>>>(E, A);
    k_cheb        <<<(NN*NN + 255)/256, 256, 0, stream>>>(A, T2);
    k_node_weights<<<14400, 256, 0, stream>>>(E, pool, Wn);
    k_node_bias   <<<75, 256, 0, stream>>>(E, bpool, bN);
    k_cvt_wout    <<<1024, 256, 0, stream>>>(Wout, Wouth);
    k_in_proj     <<<dim3(1, RTOT/64), dim3(16,16), 0, stream>>>(z, Win, bin, h);
    k_spatial     <<<dim3(NN/4, BB), 256, 0, stream>>>(A, T2, h, xg1, xg2);
    k_node_mm     <<<dim3(NN, 8), 256, 0, stream>>>(h, xg1, xg2, Wn, bN, h2h);
    k_out_proj_mfma<<<dim3(JOUT/128, RTOT/128), 256, 0, stream>>>(h2h, Wouth, bout, out);
}